// Round 3
// baseline (118.046 us; speedup 1.0000x reference)
//
#include <hip/hip_runtime.h>

typedef _Float16 half2v __attribute__((ext_vector_type(2)));
typedef _Float16 half8v __attribute__((ext_vector_type(8)));
typedef float f32x4 __attribute__((ext_vector_type(4)));
typedef unsigned uint2v __attribute__((ext_vector_type(2)));

__device__ inline half2v cvt_pk(float a, float b) {
    return __builtin_bit_cast(half2v, __builtin_amdgcn_cvt_pkrtz(a, b));
}
__device__ inline half2v pkmax0(half2v x) {
    half2v r;
    asm("v_pk_max_f16 %0, %1, 0" : "=v"(r) : "v"(x));
    return r;
}
__device__ inline unsigned short f16bits(float f) {
    _Float16 h = (_Float16)f;
    return __builtin_bit_cast(unsigned short, h);
}

// ---------------------------------------------------------------------------
// K0: src/dst = relu(LN(node @ W^T + b)) -> f16; A1 = src@W1a^T + b1 (f32);
//     B1 = dst@W1b^T (f32). One wave per (row, kind). Blocks 0..7 also pack
//     w1c / w2 into f16 MFMA A-fragment order (swapped-GEMM layout).
// ---------------------------------------------------------------------------
__global__ __launch_bounds__(256) void proj_kernel(
    const float* __restrict__ node,
    const float* __restrict__ w_src, const float* __restrict__ b_src,
    const float* __restrict__ g_src, const float* __restrict__ be_src,
    const float* __restrict__ w_dst, const float* __restrict__ b_dst,
    const float* __restrict__ g_dst, const float* __restrict__ be_dst,
    const float* __restrict__ w1, const float* __restrict__ b1,
    const float* __restrict__ w2,
    unsigned short* __restrict__ src_f16, unsigned short* __restrict__ dst_f16,
    float* __restrict__ A1, float* __restrict__ B1,
    unsigned short* __restrict__ w1c_frag, unsigned short* __restrict__ w2_frag)
{
    __shared__ float rowbuf[4][64];
    const int wloc = threadIdx.x >> 6;
    const int lane = threadIdx.x & 63;
    const int gw = blockIdx.x * 4 + wloc;     // 0..2047
    const int row = gw & 1023;
    const int kind = gw >> 10;

    const float* W  = kind ? w_dst  : w_src;
    const float* Bv = kind ? b_dst  : b_src;
    const float* G  = kind ? g_dst  : g_src;
    const float* BE = kind ? be_dst : be_src;

    const float* nrow = node + row * 128;
    const float* wrow = W + lane * 128;
    float acc = Bv[lane];
    #pragma unroll 8
    for (int k = 0; k < 128; k += 4) {
        float4 nv = *(const float4*)(nrow + k);
        float4 wv4 = *(const float4*)(wrow + k);
        acc += nv.x * wv4.x + nv.y * wv4.y + nv.z * wv4.z + nv.w * wv4.w;
    }
    // LayerNorm over 64 lanes
    float s = acc;
    #pragma unroll
    for (int off = 32; off >= 1; off >>= 1) s += __shfl_xor(s, off);
    float mean = s * (1.0f / 64.0f);
    float d = acc - mean;
    float ss = d * d;
    #pragma unroll
    for (int off = 32; off >= 1; off >>= 1) ss += __shfl_xor(ss, off);
    float rstd = rsqrtf(ss * (1.0f / 64.0f) + 1e-5f);
    float y = fmaxf(d * rstd * G[lane] + BE[lane], 0.0f);

    unsigned short* obf = kind ? dst_f16 : src_f16;
    obf[row * 64 + lane] = f16bits(y);

    rowbuf[wloc][lane] = y;
    __builtin_amdgcn_s_waitcnt(0);
    // A1[row][m] = sum_k y[k]*w1[m][koff+k] (+ b1[m] for src side)
    float* outA = kind ? B1 : A1;
    const int koff = kind * 64;
    float a0 = kind ? 0.0f : b1[lane];
    float a1 = kind ? 0.0f : b1[lane + 64];
    const float* w1r0 = w1 + (size_t)lane * 192 + koff;
    const float* w1r1 = w1 + (size_t)(lane + 64) * 192 + koff;
    #pragma unroll 4
    for (int k = 0; k < 64; k += 4) {
        float4 wa = *(const float4*)(w1r0 + k);
        float4 wb = *(const float4*)(w1r1 + k);
        float y0 = rowbuf[wloc][k], y1 = rowbuf[wloc][k+1];
        float y2 = rowbuf[wloc][k+2], y3 = rowbuf[wloc][k+3];
        a0 += y0*wa.x + y1*wa.y + y2*wa.z + y3*wa.w;
        a1 += y0*wb.x + y1*wb.y + y2*wb.z + y3*wb.w;
    }
    outA[row * 128 + lane] = a0;
    outA[row * 128 + lane + 64] = a1;

    // ---- weight packing (blocks 0..7 only) ----
    if (blockIdx.x < 8) {
        int t = blockIdx.x * 256 + threadIdx.x;   // 0..2047
        int which = t >> 10;
        int idx = t & 1023;                       // f*64 + l
        int f = idx >> 6, l = idx & 63;
        int lq = l >> 4, lr = l & 15;
        if (which == 0) {
            int mt = f >> 1, kt = f & 1;          // A-frag of W1c: row=mt*16+lr, k=kt*32+lq*8+e
            #pragma unroll
            for (int e = 0; e < 8; e++)
                w1c_frag[idx * 8 + e] =
                    f16bits(w1[(size_t)(mt * 16 + lr) * 192 + 128 + kt * 32 + lq * 8 + e]);
        } else {
            int mt2 = f >> 2, kt2 = f & 3;        // A-frag of W2: row=mt2*16+lr, k=kt2*32+lq*8+e
            #pragma unroll
            for (int e = 0; e < 8; e++)
                w2_frag[idx * 8 + e] =
                    f16bits(w2[(size_t)(mt2 * 16 + lr) * 128 + kt2 * 32 + lq * 8 + e]);
        }
    }
}

// ---------------------------------------------------------------------------
// K1: pairwise MLP, swapped-operand MFMA form.
// Block = 32 i x 32 j, 4 waves; wave owns i-rows [i0+wv*8, +8), all 32 j.
// Chunk = (one i, 16 j). GEMM1: h1t[hcol][pair] = W1c(A) x cross^T(B),
// C-init = A1[i], epilogue += B1 (packed f16) -> relu -> per-wave LDS (swizzled).
// GEMM2: h2t[m2][pair] = W2(A) x h1t(B), C-init = b2. GEMM3: in-lane dot + 2 shfl.
// ---------------------------------------------------------------------------
__global__ __launch_bounds__(256, 2) void pair_kernel(
    const unsigned short* __restrict__ src_f16, const unsigned short* __restrict__ dst_f16,
    const float* __restrict__ A1, const float* __restrict__ B1,
    const unsigned short* __restrict__ w1c_frag, const unsigned short* __restrict__ w2_frag,
    const float* __restrict__ b2, const float* __restrict__ w3,
    const float* __restrict__ b3, float* __restrict__ out)
{
    __shared__ __align__(16) unsigned short s_wf[2 * 16 * 64 * 8]; // 32 KB
    __shared__ __align__(16) char s_h1[4][4096];                   // 16 KB (per-wave 16x128 f16)

    const int tid = threadIdx.x;
    const int wv = tid >> 6;
    const int lane = tid & 63;
    const int lq = lane >> 4, lr = lane & 15;
    const int i0 = blockIdx.y * 32, j0 = blockIdx.x * 32;

    // ---- stage weight frags into LDS (coalesced), then into regs ----
    {
        const uint4* gw1 = (const uint4*)w1c_frag;  // 1024 x 16B
        const uint4* gw2 = (const uint4*)w2_frag;   // 1024 x 16B
        uint4* sw = (uint4*)s_wf;
        #pragma unroll
        for (int u = tid; u < 2048; u += 256)
            sw[u] = (u < 1024) ? gw1[u] : gw2[u - 1024];
    }

    // scalar-ish preloads (no sync needed)
    f32x4 b2v[4], w3v[4];
    #pragma unroll
    for (int mt2 = 0; mt2 < 4; mt2++) {
        b2v[mt2] = *(const f32x4*)(b2 + mt2 * 16 + lq * 4);
        w3v[mt2] = *(const f32x4*)(w3 + mt2 * 16 + lq * 4);
    }
    const float b3v = b3[0];

    __syncthreads();

    half8v w1f[8][2], w2f[4][4];
    {
        const half8v* wlds = (const half8v*)s_wf;
        #pragma unroll
        for (int mt = 0; mt < 8; mt++)
            #pragma unroll
            for (int kt = 0; kt < 2; kt++)
                w1f[mt][kt] = wlds[(mt * 2 + kt) * 64 + lane];
        #pragma unroll
        for (int mt2 = 0; mt2 < 4; mt2++)
            #pragma unroll
            for (int kt = 0; kt < 4; kt++)
                w2f[mt2][kt] = wlds[1024 + (mt2 * 4 + kt) * 64 + lane];
    }

    char* myh = &s_h1[wv][0] + lr * 256;
    const int swz = (lr & 7) << 4;

    for (int jb = 0; jb < 32; jb += 16) {
        const int j = j0 + jb + lr;
        // dst B-frag slices for this j (reused across all 8 i's)
        const uint4* drow = (const uint4*)(dst_f16 + (size_t)j * 64);
        const half8v dstf0 = __builtin_bit_cast(half8v, drow[lq]);
        const half8v dstf1 = __builtin_bit_cast(half8v, drow[4 + lq]);
        // B1 for this j, packed f16 pairs matching acc layout
        half2v b1pk[8][2];
        #pragma unroll
        for (int mt = 0; mt < 8; mt++) {
            float4 v = *(const float4*)(B1 + (size_t)j * 128 + mt * 16 + lq * 4);
            b1pk[mt][0] = cvt_pk(v.x, v.y);
            b1pk[mt][1] = cvt_pk(v.z, v.w);
        }

        for (int ii = 0; ii < 8; ii++) {
            const int i = i0 + wv * 8 + ii;
            // src slices (broadcast across lr)
            const uint4* srow = (const uint4*)(src_f16 + (size_t)i * 64);
            const half8v s0 = __builtin_bit_cast(half8v, srow[lq]);
            const half8v s1 = __builtin_bit_cast(half8v, srow[4 + lq]);
            // A1 straight into accumulator (C-init)
            f32x4 acc1[8];
            #pragma unroll
            for (int mt = 0; mt < 8; mt++)
                acc1[mt] = *(const f32x4*)(A1 + (size_t)i * 128 + mt * 16 + lq * 4);
            // cross features: B-frags of cross^T (pair = lr)
            const half8v c0 = s0 * dstf0;
            const half8v c1 = s1 * dstf1;
            // GEMM1: h1t = W1c x cross^T + A1
            #pragma unroll
            for (int mt = 0; mt < 8; mt++) {
                acc1[mt] = __builtin_amdgcn_mfma_f32_16x16x32_f16(w1f[mt][0], c0, acc1[mt], 0, 0, 0);
                acc1[mt] = __builtin_amdgcn_mfma_f32_16x16x32_f16(w1f[mt][1], c1, acc1[mt], 0, 0, 0);
            }
            // epilogue: +B1, relu, pack f16, swizzled b64 write
            #pragma unroll
            for (int mt = 0; mt < 8; mt++) {
                half2v p0 = cvt_pk(acc1[mt][0], acc1[mt][1]) + b1pk[mt][0];
                half2v p1 = cvt_pk(acc1[mt][2], acc1[mt][3]) + b1pk[mt][1];
                p0 = pkmax0(p0);
                p1 = pkmax0(p1);
                uint2v wv2 = { __builtin_bit_cast(unsigned, p0), __builtin_bit_cast(unsigned, p1) };
                *(uint2v*)(myh + ((mt * 32 + lq * 8) ^ swz)) = wv2;
            }
            // order LDS write -> read within the wave
            asm volatile("s_waitcnt lgkmcnt(0)" ::: "memory");
            // GEMM2 B-frags: swizzled b128 reads of own pair-row
            half8v hf[4];
            #pragma unroll
            for (int kt = 0; kt < 4; kt++)
                hf[kt] = *(const half8v*)(myh + ((kt * 64 + lq * 16) ^ swz));
            f32x4 acc2[4];
            #pragma unroll
            for (int mt2 = 0; mt2 < 4; mt2++) acc2[mt2] = b2v[mt2];
            #pragma unroll
            for (int kt = 0; kt < 4; kt++)
                #pragma unroll
                for (int mt2 = 0; mt2 < 4; mt2++)
                    acc2[mt2] = __builtin_amdgcn_mfma_f32_16x16x32_f16(w2f[mt2][kt], hf[kt], acc2[mt2], 0, 0, 0);
            // GEMM3: out = relu(h2) . w3, reduce across lq groups
            float part = 0.0f;
            #pragma unroll
            for (int mt2 = 0; mt2 < 4; mt2++)
                #pragma unroll
                for (int r = 0; r < 4; r++)
                    part += fmaxf(acc2[mt2][r], 0.0f) * w3v[mt2][r];
            part += __shfl_xor(part, 16);
            part += __shfl_xor(part, 32);
            if (lane < 16)
                out[(size_t)i * 1024 + j0 + jb + lane] = part + b3v;
        }
    }
}

// ---------------------------------------------------------------------------
extern "C" void kernel_launch(void* const* d_in, const int* in_sizes, int n_in,
                              void* d_out, int out_size, void* d_ws, size_t ws_size,
                              hipStream_t stream) {
    (void)in_sizes; (void)n_in; (void)out_size; (void)ws_size;
    const float* node   = (const float*)d_in[0];
    const float* w_src  = (const float*)d_in[1];
    const float* b_src  = (const float*)d_in[2];
    const float* g_src  = (const float*)d_in[3];
    const float* be_src = (const float*)d_in[4];
    const float* w_dst  = (const float*)d_in[5];
    const float* b_dst  = (const float*)d_in[6];
    const float* g_dst  = (const float*)d_in[7];
    const float* be_dst = (const float*)d_in[8];
    const float* w1     = (const float*)d_in[9];
    const float* b1     = (const float*)d_in[10];
    const float* w2     = (const float*)d_in[11];
    const float* b2     = (const float*)d_in[12];
    const float* w3     = (const float*)d_in[13];
    const float* b3     = (const float*)d_in[14];

    char* ws = (char*)d_ws;
    unsigned short* src_f16  = (unsigned short*)(ws);
    unsigned short* dst_f16  = (unsigned short*)(ws + 131072);
    float*          A1       = (float*)(ws + 262144);
    float*          B1       = (float*)(ws + 786432);
    unsigned short* w1c_frag = (unsigned short*)(ws + 1310720);
    unsigned short* w2_frag  = (unsigned short*)(ws + 1327104);

    hipLaunchKernelGGL(proj_kernel, dim3(512), dim3(256), 0, stream,
                       node, w_src, b_src, g_src, be_src, w_dst, b_dst, g_dst, be_dst,
                       w1, b1, w2, src_f16, dst_f16, A1, B1, w1c_frag, w2_frag);
    hipLaunchKernelGGL(pair_kernel, dim3(32, 32), dim3(256), 0, stream,
                       src_f16, dst_f16, A1, B1, w1c_frag, w2_frag, b2, w3, b3,
                       (float*)d_out);
}

// Round 4
// 80.847 us; speedup vs baseline: 1.4601x; 1.4601x over previous
//
#include <hip/hip_runtime.h>

typedef _Float16 half2v __attribute__((ext_vector_type(2)));
typedef _Float16 half8v __attribute__((ext_vector_type(8)));
typedef float f32x4 __attribute__((ext_vector_type(4)));
typedef unsigned uint2v __attribute__((ext_vector_type(2)));

__device__ inline half2v cvt_pk(float a, float b) {
    return __builtin_bit_cast(half2v, __builtin_amdgcn_cvt_pkrtz(a, b));
}
__device__ inline half2v pkmax0(half2v x) {
    half2v r;
    asm("v_pk_max_f16 %0, %1, 0" : "=v"(r) : "v"(x));
    return r;
}
__device__ inline unsigned short f16bits(float f) {
    _Float16 h = (_Float16)f;
    return __builtin_bit_cast(unsigned short, h);
}

// ---------------------------------------------------------------------------
// K0: src/dst = relu(LN(node @ W^T + b)) -> f16; A1 = src@W1a^T + b1 (f32);
//     B1h = dst@W1b^T (f16, packed for pair_kernel's per-lane adds).
//     Blocks 0..7 also pack w1c / w2 into f16 MFMA A-fragment order.
//     w2 is packed with the sigma k-permutation so GEMM2's B-operand is the
//     epilogue's own registers (no h1 transpose needed):
//       sigma(kt, lq*8+e) = (2*kt + (e>>2))*16 + lq*4 + (e&3)
// ---------------------------------------------------------------------------
__global__ __launch_bounds__(256) void proj_kernel(
    const float* __restrict__ node,
    const float* __restrict__ w_src, const float* __restrict__ b_src,
    const float* __restrict__ g_src, const float* __restrict__ be_src,
    const float* __restrict__ w_dst, const float* __restrict__ b_dst,
    const float* __restrict__ g_dst, const float* __restrict__ be_dst,
    const float* __restrict__ w1, const float* __restrict__ b1,
    const float* __restrict__ w2,
    unsigned short* __restrict__ src_f16, unsigned short* __restrict__ dst_f16,
    float* __restrict__ A1, unsigned short* __restrict__ B1h,
    unsigned short* __restrict__ w1c_frag, unsigned short* __restrict__ w2_frag)
{
    __shared__ float rowbuf[4][64];
    const int wloc = threadIdx.x >> 6;
    const int lane = threadIdx.x & 63;
    const int gw = blockIdx.x * 4 + wloc;     // 0..2047
    const int row = gw & 1023;
    const int kind = gw >> 10;

    const float* W  = kind ? w_dst  : w_src;
    const float* Bv = kind ? b_dst  : b_src;
    const float* G  = kind ? g_dst  : g_src;
    const float* BE = kind ? be_dst : be_src;

    const float* nrow = node + row * 128;
    const float* wrow = W + lane * 128;
    float acc = Bv[lane];
    #pragma unroll 8
    for (int k = 0; k < 128; k += 4) {
        float4 nv = *(const float4*)(nrow + k);
        float4 wv4 = *(const float4*)(wrow + k);
        acc += nv.x * wv4.x + nv.y * wv4.y + nv.z * wv4.z + nv.w * wv4.w;
    }
    // LayerNorm over 64 lanes
    float s = acc;
    #pragma unroll
    for (int off = 32; off >= 1; off >>= 1) s += __shfl_xor(s, off);
    float mean = s * (1.0f / 64.0f);
    float d = acc - mean;
    float ss = d * d;
    #pragma unroll
    for (int off = 32; off >= 1; off >>= 1) ss += __shfl_xor(ss, off);
    float rstd = rsqrtf(ss * (1.0f / 64.0f) + 1e-5f);
    float y = fmaxf(d * rstd * G[lane] + BE[lane], 0.0f);

    unsigned short* obf = kind ? dst_f16 : src_f16;
    obf[row * 64 + lane] = f16bits(y);

    rowbuf[wloc][lane] = y;
    __builtin_amdgcn_s_waitcnt(0);
    // A1[row][m] = sum_k y[k]*w1[m][koff+k] (+ b1[m] for src side)
    const int koff = kind * 64;
    float a0 = kind ? 0.0f : b1[lane];
    float a1 = kind ? 0.0f : b1[lane + 64];
    const float* w1r0 = w1 + (size_t)lane * 192 + koff;
    const float* w1r1 = w1 + (size_t)(lane + 64) * 192 + koff;
    #pragma unroll 4
    for (int k = 0; k < 64; k += 4) {
        float4 wa = *(const float4*)(w1r0 + k);
        float4 wb = *(const float4*)(w1r1 + k);
        float y0 = rowbuf[wloc][k], y1 = rowbuf[wloc][k+1];
        float y2 = rowbuf[wloc][k+2], y3 = rowbuf[wloc][k+3];
        a0 += y0*wa.x + y1*wa.y + y2*wa.z + y3*wa.w;
        a1 += y0*wb.x + y1*wb.y + y2*wb.z + y3*wb.w;
    }
    if (kind == 0) {
        A1[row * 128 + lane] = a0;
        A1[row * 128 + lane + 64] = a1;
    } else {
        B1h[row * 128 + lane] = f16bits(a0);
        B1h[row * 128 + lane + 64] = f16bits(a1);
    }

    // ---- weight packing (blocks 0..7 only) ----
    if (blockIdx.x < 8) {
        int t = blockIdx.x * 256 + threadIdx.x;   // 0..2047
        int which = t >> 10;
        int idx = t & 1023;                       // f*64 + l
        int f = idx >> 6, l = idx & 63;
        int lq = l >> 4, lr = l & 15;
        if (which == 0) {
            int mt = f >> 1, kt = f & 1;          // A-frag of W1c: row=mt*16+lr, k=kt*32+lq*8+e
            #pragma unroll
            for (int e = 0; e < 8; e++)
                w1c_frag[idx * 8 + e] =
                    f16bits(w1[(size_t)(mt * 16 + lr) * 192 + 128 + kt * 32 + lq * 8 + e]);
        } else {
            int mt2 = f >> 2, kt2 = f & 3;        // A-frag of W2 with sigma permutation
            #pragma unroll
            for (int e = 0; e < 8; e++) {
                int col = (2 * kt2 + (e >> 2)) * 16 + lq * 4 + (e & 3);
                w2_frag[idx * 8 + e] =
                    f16bits(w2[(size_t)(mt2 * 16 + lr) * 128 + col]);
            }
        }
    }
}

// ---------------------------------------------------------------------------
// K1: pairwise MLP, swapped-operand MFMA form, no h1 LDS round-trip.
// Block = 32 i x 32 j, 4 waves; wave owns i-rows [i0+wv*8, +8), all 32 j.
// Chunk = (one i, 16 j = lr). GEMM1: h1t = W1c(A) x cross^T(B), C-init = A1[i].
// Epilogue: +B1h (f16), relu, pack -> P[16] regs.
// GEMM2: B-frag kt = P[4kt..4kt+3] (sigma-permuted W2). C-init = b2.
// GEMM3: f32 dot + 2 shfl_xor.
// ---------------------------------------------------------------------------
__global__ __launch_bounds__(256, 1) void pair_kernel(
    const unsigned short* __restrict__ src_f16, const unsigned short* __restrict__ dst_f16,
    const float* __restrict__ A1, const unsigned short* __restrict__ B1h,
    const unsigned short* __restrict__ w1c_frag, const unsigned short* __restrict__ w2_frag,
    const float* __restrict__ b2, const float* __restrict__ w3,
    const float* __restrict__ b3, float* __restrict__ out)
{
    __shared__ __align__(16) unsigned short s_wf[2 * 16 * 64 * 8]; // 32 KB

    const int tid = threadIdx.x;
    const int wv = tid >> 6;
    const int lane = tid & 63;
    const int lq = lane >> 4, lr = lane & 15;
    const int i0 = blockIdx.y * 32, j0 = blockIdx.x * 32;

    // ---- stage weight frags into LDS (coalesced), then into regs ----
    {
        const uint4* gw1 = (const uint4*)w1c_frag;  // 1024 x 16B
        const uint4* gw2 = (const uint4*)w2_frag;   // 1024 x 16B
        uint4* sw = (uint4*)s_wf;
        #pragma unroll
        for (int u = tid; u < 2048; u += 256)
            sw[u] = (u < 1024) ? gw1[u] : gw2[u - 1024];
    }

    f32x4 b2v[4], w3v[4];
    #pragma unroll
    for (int mt2 = 0; mt2 < 4; mt2++) {
        b2v[mt2] = *(const f32x4*)(b2 + mt2 * 16 + lq * 4);
        w3v[mt2] = *(const f32x4*)(w3 + mt2 * 16 + lq * 4);
    }
    const float b3v = b3[0];

    __syncthreads();

    half8v w1f[8][2], w2f[4][4];
    {
        const half8v* wlds = (const half8v*)s_wf;
        #pragma unroll
        for (int mt = 0; mt < 8; mt++)
            #pragma unroll
            for (int kt = 0; kt < 2; kt++)
                w1f[mt][kt] = wlds[(mt * 2 + kt) * 64 + lane];
        #pragma unroll
        for (int mt2 = 0; mt2 < 4; mt2++)
            #pragma unroll
            for (int kt = 0; kt < 4; kt++)
                w2f[mt2][kt] = wlds[1024 + (mt2 * 4 + kt) * 64 + lane];
    }

    for (int jb = 0; jb < 32; jb += 16) {
        const int j = j0 + jb + lr;
        // dst B-frag slices for this j (reused across all 8 i's)
        const uint4* drow = (const uint4*)(dst_f16 + (size_t)j * 64);
        const half8v dstf0 = __builtin_bit_cast(half8v, drow[lq]);
        const half8v dstf1 = __builtin_bit_cast(half8v, drow[4 + lq]);
        // B1 for this j: f16-packed pairs matching acc layout (8B loads)
        half2v b1pk[8][2];
        #pragma unroll
        for (int mt = 0; mt < 8; mt++) {
            uint2v bl = *(const uint2v*)(B1h + (size_t)j * 128 + mt * 16 + lq * 4);
            b1pk[mt][0] = __builtin_bit_cast(half2v, bl[0]);
            b1pk[mt][1] = __builtin_bit_cast(half2v, bl[1]);
        }

        #pragma unroll
        for (int ii = 0; ii < 8; ii++) {
            const int i = i0 + wv * 8 + ii;
            // src slices (broadcast across lr)
            const uint4* srow = (const uint4*)(src_f16 + (size_t)i * 64);
            const half8v s0 = __builtin_bit_cast(half8v, srow[lq]);
            const half8v s1 = __builtin_bit_cast(half8v, srow[4 + lq]);
            // A1 straight into accumulator (C-init)
            f32x4 acc1[8];
            #pragma unroll
            for (int mt = 0; mt < 8; mt++)
                acc1[mt] = *(const f32x4*)(A1 + (size_t)i * 128 + mt * 16 + lq * 4);
            // cross features: B-frags of cross^T (pair = lr)
            const half8v c0 = s0 * dstf0;
            const half8v c1 = s1 * dstf1;
            // GEMM1: h1t = W1c x cross^T + A1
            #pragma unroll
            for (int mt = 0; mt < 8; mt++) {
                acc1[mt] = __builtin_amdgcn_mfma_f32_16x16x32_f16(w1f[mt][0], c0, acc1[mt], 0, 0, 0);
                acc1[mt] = __builtin_amdgcn_mfma_f32_16x16x32_f16(w1f[mt][1], c1, acc1[mt], 0, 0, 0);
            }
            // epilogue: +B1, relu, pack f16 into P (feeds GEMM2 directly)
            unsigned P[16];
            #pragma unroll
            for (int mt = 0; mt < 8; mt++) {
                half2v p0 = cvt_pk(acc1[mt][0], acc1[mt][1]) + b1pk[mt][0];
                half2v p1 = cvt_pk(acc1[mt][2], acc1[mt][3]) + b1pk[mt][1];
                P[mt * 2 + 0] = __builtin_bit_cast(unsigned, pkmax0(p0));
                P[mt * 2 + 1] = __builtin_bit_cast(unsigned, pkmax0(p1));
            }
            // GEMM2: sigma-permuted W2 x h1t; B-frag = own P regs
            f32x4 acc2[4];
            #pragma unroll
            for (int mt2 = 0; mt2 < 4; mt2++) acc2[mt2] = b2v[mt2];
            #pragma unroll
            for (int kt = 0; kt < 4; kt++) {
                uint4 hb = {P[4 * kt], P[4 * kt + 1], P[4 * kt + 2], P[4 * kt + 3]};
                half8v hf = __builtin_bit_cast(half8v, hb);
                #pragma unroll
                for (int mt2 = 0; mt2 < 4; mt2++)
                    acc2[mt2] = __builtin_amdgcn_mfma_f32_16x16x32_f16(w2f[mt2][kt], hf, acc2[mt2], 0, 0, 0);
            }
            // GEMM3: out = relu(h2) . w3 (f32), reduce across lq groups
            float part = 0.0f;
            #pragma unroll
            for (int mt2 = 0; mt2 < 4; mt2++)
                #pragma unroll
                for (int r = 0; r < 4; r++)
                    part += fmaxf(acc2[mt2][r], 0.0f) * w3v[mt2][r];
            part += __shfl_xor(part, 16);
            part += __shfl_xor(part, 32);
            if (lane < 16)
                out[(size_t)i * 1024 + j0 + jb + lane] = part + b3v;
        }
    }
}

// ---------------------------------------------------------------------------
extern "C" void kernel_launch(void* const* d_in, const int* in_sizes, int n_in,
                              void* d_out, int out_size, void* d_ws, size_t ws_size,
                              hipStream_t stream) {
    (void)in_sizes; (void)n_in; (void)out_size; (void)ws_size;
    const float* node   = (const float*)d_in[0];
    const float* w_src  = (const float*)d_in[1];
    const float* b_src  = (const float*)d_in[2];
    const float* g_src  = (const float*)d_in[3];
    const float* be_src = (const float*)d_in[4];
    const float* w_dst  = (const float*)d_in[5];
    const float* b_dst  = (const float*)d_in[6];
    const float* g_dst  = (const float*)d_in[7];
    const float* be_dst = (const float*)d_in[8];
    const float* w1     = (const float*)d_in[9];
    const float* b1     = (const float*)d_in[10];
    const float* w2     = (const float*)d_in[11];
    const float* b2     = (const float*)d_in[12];
    const float* w3     = (const float*)d_in[13];
    const float* b3     = (const float*)d_in[14];

    char* ws = (char*)d_ws;
    unsigned short* src_f16  = (unsigned short*)(ws);
    unsigned short* dst_f16  = (unsigned short*)(ws + 131072);
    float*          A1       = (float*)(ws + 262144);
    unsigned short* B1h      = (unsigned short*)(ws + 786432);
    unsigned short* w1c_frag = (unsigned short*)(ws + 1310720);
    unsigned short* w2_frag  = (unsigned short*)(ws + 1327104);

    hipLaunchKernelGGL(proj_kernel, dim3(512), dim3(256), 0, stream,
                       node, w_src, b_src, g_src, be_src, w_dst, b_dst, g_dst, be_dst,
                       w1, b1, w2, src_f16, dst_f16, A1, B1h, w1c_frag, w2_frag);
    hipLaunchKernelGGL(pair_kernel, dim3(32, 32), dim3(256), 0, stream,
                       src_f16, dst_f16, A1, B1h, w1c_frag, w2_frag, b2, w3, b3,
                       (float*)d_out);
}